// Round 5
// baseline (284.558 us; speedup 1.0000x reference)
//
#include <hip/hip_runtime.h>
#include <math.h>

#define N_NODES 2048
#define N1S 36   // padded n1 row stride (16B-aligned rows)
#define NB  256  // grid size == #CUs -> all blocks co-resident (1 block/CU, 24KB LDS)

__device__ __forceinline__ float invdeg(int j) { return j > 0 ? 1.0f / (float)j : 0.0f; }

// Distributed grid barrier (monotonic, no RMW, no shared-line ping-pong):
//  - arrival: each block release-stores phase+1 to its OWN 128B-spaced flag
//  - detect:  block 0's thread t acquire-polls flag[t] (256 independent lines)
//  - publish: block 0 thread 0 release-stores epoch = phase+1
//  - wait:    other blocks acquire-poll epoch (read-only shared line)
// HB chain: producer rel(flag) -> blk0 acq -> __syncthreads -> rel(epoch) -> acq. XCD-safe.
__device__ __forceinline__ void gbar(int* flags, int* epoch, int phase) {
  const int target = phase + 1;
  const int bx = blockIdx.x;
  const int tid = threadIdx.x;
  __syncthreads();
  if (bx == 0) {
    if (tid > 0) {
      while (__hip_atomic_load(&flags[tid * 32], __ATOMIC_ACQUIRE,
                               __HIP_MEMORY_SCOPE_AGENT) < target)
        __builtin_amdgcn_s_sleep(2);
    }
    __syncthreads();
    if (tid == 0)
      __hip_atomic_store(epoch, target, __ATOMIC_RELEASE, __HIP_MEMORY_SCOPE_AGENT);
  } else {
    if (tid == 0) {
      __hip_atomic_store(&flags[bx * 32], target, __ATOMIC_RELEASE,
                         __HIP_MEMORY_SCOPE_AGENT);
      while (__hip_atomic_load(epoch, __ATOMIC_ACQUIRE,
                               __HIP_MEMORY_SCOPE_AGENT) < target)
        __builtin_amdgcn_s_sleep(2);
    }
    __syncthreads();
  }
}

__global__ __launch_bounds__(256) void k_fused(
    const float* __restrict__ x, const float* __restrict__ cent,
    const float* __restrict__ Ws1, const float* __restrict__ Wn1,
    const float* __restrict__ b1, const float* __restrict__ Ws2,
    const float* __restrict__ Wn2, const float* __restrict__ b2,
    const float* __restrict__ Wm1, const float* __restrict__ bm1,
    const float* __restrict__ Wm2, const float* __restrict__ bm2,
    float* __restrict__ n1, float* __restrict__ h1, float* __restrict__ h1T,
    float* __restrict__ n2, float* __restrict__ A, float* __restrict__ Bm,
    int* flags, int* epoch, float2* __restrict__ out) {
  __shared__ float smem[6144];  // 24 KB, reused across phases
  const int tid = threadIdx.x;
  const int bx = blockIdx.x;
  const int wv = tid >> 6;
  const int lane = tid & 63;

  // ---------------- Phase 1: edge features -> n1 ----------------
  if (bx < 32) {
    // per-feature exclusive scan of x[i,f]^2/||x_i||  (f = bx)
    float* invn_s = smem;        // 2048
    float* sc = smem + 2048;     // 256
    const int f = bx;
    for (int r = 0; r < 8; ++r) {
      int n = tid + 256 * r;
      const float4* xp = (const float4*)(x + n * 32);
      float s = 0.f;
#pragma unroll
      for (int q = 0; q < 8; ++q) {
        float4 v = xp[q];
        s += v.x * v.x + v.y * v.y + v.z * v.z + v.w * v.w;
      }
      invn_s[n] = rsqrtf(s);
    }
    __syncthreads();
    float sv[8], xv[8];
    float ts = 0.f;
#pragma unroll
    for (int r = 0; r < 8; ++r) {
      int i = tid * 8 + r;
      float xf = x[i * 32 + f];
      xv[r] = xf;
      float s = xf * xf * invn_s[i];
      sv[r] = s;
      ts += s;
    }
    sc[tid] = ts;
    __syncthreads();
    for (int off = 1; off < 256; off <<= 1) {
      float v = (tid >= off) ? sc[tid - off] : 0.f;
      __syncthreads();
      sc[tid] += v;
      __syncthreads();
    }
    float P = sc[tid] - ts;
#pragma unroll
    for (int r = 0; r < 8; ++r) {
      int i = tid * 8 + r;
      n1[i * N1S + f] = P * xv[r] * invn_s[i] * invdeg(i);
      P += sv[r];
    }
  } else {
    // centroid |diff| sums; wave handles pairs (p, 2047-p)
    float* cs = smem;  // 6144
    const float4* cp = (const float4*)cent;
    float4* csp = (float4*)cs;
#pragma unroll
    for (int q = 0; q < 6; ++q) csp[tid + 256 * q] = cp[tid + 256 * q];
    __syncthreads();
    const int wvg = (bx - 32) * 4 + wv;  // 0..895
#pragma unroll
    for (int rep = 0; rep < 2; ++rep) {
      const int p = wvg + rep * 896;
      if (p < 1024) {
#pragma unroll
        for (int pick = 0; pick < 2; ++pick) {
          const int j = pick ? (2047 - p) : p;
          const float cj0 = cs[j * 3 + 0], cj1 = cs[j * 3 + 1], cj2 = cs[j * 3 + 2];
          float s0 = 0.f, s1 = 0.f, s2 = 0.f;
          for (int i = lane; i < j; i += 64) {
            float c0 = cs[i * 3 + 0], c1 = cs[i * 3 + 1], c2 = cs[i * 3 + 2];
            s0 += c0 * fabsf(c0 - cj0);
            s1 += c1 * fabsf(c1 - cj1);
            s2 += c2 * fabsf(c2 - cj2);
          }
#pragma unroll
          for (int d = 32; d > 0; d >>= 1) {
            s0 += __shfl_down(s0, d);
            s1 += __shfl_down(s1, d);
            s2 += __shfl_down(s2, d);
          }
          if (lane == 0) {
            float idg = invdeg(j);
            n1[j * N1S + 32] = s0 * idg;
            n1[j * N1S + 33] = s1 * idg;
            n1[j * N1S + 34] = s2 * idg;
          }
        }
      }
    }
  }
  gbar(flags, epoch, 0);

  // ---------------- Phase 2: h1 (+ transposed copy h1T) ----------------
  {
    const int gw = bx * 4 + wv;  // 0..1023, wave-per-node, 2 rounds
    const int o = lane;
#pragma unroll
    for (int r = 0; r < 2; ++r) {
      const int n = __builtin_amdgcn_readfirstlane(gw + 1024 * r);
      float acc = b1[o];
      const float4* xr = (const float4*)(x + n * 32);
      const float4* nr = (const float4*)(n1 + n * N1S);
#pragma unroll
      for (int q = 0; q < 8; ++q) {
        float4 xv = xr[q];
        float4 nv = nr[q];
        acc += xv.x * Ws1[(4 * q + 0) * 64 + o] + nv.x * Wn1[(4 * q + 0) * 64 + o];
        acc += xv.y * Ws1[(4 * q + 1) * 64 + o] + nv.y * Wn1[(4 * q + 1) * 64 + o];
        acc += xv.z * Ws1[(4 * q + 2) * 64 + o] + nv.z * Wn1[(4 * q + 2) * 64 + o];
        acc += xv.w * Ws1[(4 * q + 3) * 64 + o] + nv.w * Wn1[(4 * q + 3) * 64 + o];
      }
      {
        float4 nv = nr[8];
        float c0 = cent[n * 3 + 0], c1 = cent[n * 3 + 1], c2 = cent[n * 3 + 2];
        acc += c0 * Ws1[32 * 64 + o] + nv.x * Wn1[32 * 64 + o];
        acc += c1 * Ws1[33 * 64 + o] + nv.y * Wn1[33 * 64 + o];
        acc += c2 * Ws1[34 * 64 + o] + nv.z * Wn1[34 * 64 + o];
      }
      h1[n * 64 + o] = acc;
      h1T[o * N_NODES + n] = acc;
    }
  }
  gbar(flags, epoch, 1);

  // ---------------- Phase 3: column scan of h1 -> n2 ----------------
  if (bx < 64) {
    float* sc = smem;
    const int o = bx;
    float sv[8];
    const float4* colp = (const float4*)(h1T + o * N_NODES);
    float4 a = colp[2 * tid];
    float4 b = colp[2 * tid + 1];
    sv[0] = a.x; sv[1] = a.y; sv[2] = a.z; sv[3] = a.w;
    sv[4] = b.x; sv[5] = b.y; sv[6] = b.z; sv[7] = b.w;
    float ts = 0.f;
#pragma unroll
    for (int r = 0; r < 8; ++r) ts += sv[r];
    sc[tid] = ts;
    __syncthreads();
    for (int off = 1; off < 256; off <<= 1) {
      float v = (tid >= off) ? sc[tid - off] : 0.f;
      __syncthreads();
      sc[tid] += v;
      __syncthreads();
    }
    float P = sc[tid] - ts;
#pragma unroll
    for (int r = 0; r < 8; ++r) {
      int i = tid * 8 + r;
      n2[i * 64 + o] = P * invdeg(i);
      P += sv[r];
    }
  }
  gbar(flags, epoch, 2);

  // ---------------- Phase 4: h2 -> A, Bm ----------------
  {
    const int gw = bx * 4 + wv;  // wave-per-node, 2 rounds
    const int o = lane & 31;
    const int half = lane >> 5;
#pragma unroll
    for (int r = 0; r < 2; ++r) {
      const int n = __builtin_amdgcn_readfirstlane(gw + 1024 * r);
      float acc = b2[o];
#pragma unroll
      for (int f = 0; f < 64; ++f)
        acc += h1[n * 64 + f] * Ws2[f * 32 + o] + n2[n * 64 + f] * Wn2[f * 32 + o];
      __syncthreads();
      smem[wv * 32 + o] = acc;  // both halves write identical value
      __syncthreads();
      float rr = half ? bm1[o] : 0.f;
#pragma unroll
      for (int f = 0; f < 32; ++f)
        rr += smem[wv * 32 + f] * Wm1[(half * 32 + f) * 32 + o];
      if (half)
        Bm[n * 32 + o] = rr;
      else
        A[n * 32 + o] = rr;
    }
  }
  gbar(flags, epoch, 3);

  // ---------------- Phase 5: per-edge head ----------------
  {
    float wd[32];
#pragma unroll
    for (int f = 0; f < 32; ++f) wd[f] = Wm2[f * 2 + 1] - Wm2[f * 2];
    const float db = bm2[1] - bm2[0];
    // 1152 chunks of 8 i-rows x 256 j-cols, linearized over jt: offset 16*jt*(jt+1)
    for (int c = bx; c < 1152; c += NB) {
      int jt = 0;
#pragma unroll
      for (int t = 1; t < 8; ++t)
        if (c >= 16 * t * (t + 1)) jt = t;
      const int ic = c - 16 * jt * (jt + 1);
      const int j0 = jt * 256;
      const int i0 = ic * 8;
      const int j = j0 + tid;
      float Br[32];
      const float4* bp = (const float4*)(Bm + j * 32);
#pragma unroll
      for (int q = 0; q < 8; ++q) {
        float4 v = bp[q];
        Br[4 * q + 0] = v.x;
        Br[4 * q + 1] = v.y;
        Br[4 * q + 2] = v.z;
        Br[4 * q + 3] = v.w;
      }
#pragma unroll
      for (int ii = 0; ii < 8; ++ii) {
        const int i = i0 + ii;
        const float* Ar = A + i * 32;  // uniform row -> scalar loads
        float d = db;
#pragma unroll
        for (int f = 0; f < 32; ++f)
          d += fmaxf(Ar[f] + Br[f], 0.f) * wd[f];
        if (i < j) {
          float p0 = 1.0f / (1.0f + __expf(d));
          int e = i * (2 * N_NODES - 1 - i) / 2 + (j - i - 1);
          out[e] = make_float2(p0, 1.0f - p0);
        }
      }
    }
  }
}

extern "C" void kernel_launch(void* const* d_in, const int* in_sizes, int n_in,
                              void* d_out, int out_size, void* d_ws, size_t ws_size,
                              hipStream_t stream) {
  const float* x    = (const float*)d_in[0];
  const float* cent = (const float*)d_in[1];
  const float* Ws1  = (const float*)d_in[2];
  const float* Wn1  = (const float*)d_in[3];
  const float* b1   = (const float*)d_in[4];
  const float* Ws2  = (const float*)d_in[5];
  const float* Wn2  = (const float*)d_in[6];
  const float* b2   = (const float*)d_in[7];
  const float* Wm1  = (const float*)d_in[8];
  const float* bm1  = (const float*)d_in[9];
  const float* Wm2  = (const float*)d_in[10];
  const float* bm2  = (const float*)d_in[11];

  int* flags = (int*)d_ws;                       // 256 flags, 128B apart (32 KB)
  int* epoch = flags + 256 * 32;                 // own line
  float* base = (float*)((char*)d_ws + 65536);   // data region after 64 KB
  float* n1  = base;                    // 2048*36
  float* h1  = n1 + 2048 * N1S;         // 2048*64
  float* h1T = h1 + 2048 * 64;          // 64*2048
  float* n2  = h1T + 2048 * 64;         // 2048*64
  float* A   = n2 + 2048 * 64;          // 2048*32
  float* Bm  = A + 2048 * 32;           // 2048*32

  hipMemsetAsync(d_ws, 0, 36864, stream);  // zero flags + epoch (capturable)
  k_fused<<<NB, 256, 0, stream>>>(x, cent, Ws1, Wn1, b1, Ws2, Wn2, b2,
                                  Wm1, bm1, Wm2, bm2,
                                  n1, h1, h1T, n2, A, Bm, flags, epoch,
                                  (float2*)d_out);
}

// Round 6
// 156.202 us; speedup vs baseline: 1.8217x; 1.8217x over previous
//
#include <hip/hip_runtime.h>
#include <math.h>

#define N_NODES 2048
#define N1S 36   // padded n1 row stride (16B-aligned rows)
#define NB  256  // grid size == #CUs -> all blocks co-resident (1 block/CU, 24KB LDS)

__device__ __forceinline__ float invdeg(int j) { return j > 0 ? 1.0f / (float)j : 0.0f; }

// Distributed grid barrier with RELAXED polling (no per-poll cache ops):
//  - producer: ONE release fence (wbl2) then relaxed store to own 128B-spaced flag
//  - block 0 thread t: relaxed-polls flag[t] (sc1 coherence-point reads, no inv)
//  - block 0: ONE acquire fence, ONE release fence, relaxed store epoch
//  - others: relaxed-poll epoch, then ONE acquire fence
// HB: rel-fence->flag ... flag-poll->acq-fence (fence pairing) — XCD-safe.
__device__ __forceinline__ void gbar(int* flags, int* epoch, int phase) {
  const int target = phase + 1;
  const int bx = blockIdx.x;
  const int tid = threadIdx.x;
  __syncthreads();
  if (bx == 0) {
    if (tid > 0) {
      while (__hip_atomic_load(&flags[tid * 32], __ATOMIC_RELAXED,
                               __HIP_MEMORY_SCOPE_AGENT) < target)
        __builtin_amdgcn_s_sleep(8);
    }
    __syncthreads();
    if (tid == 0) {
      __builtin_amdgcn_fence(__ATOMIC_ACQUIRE, "agent");  // see producers' writes
      __builtin_amdgcn_fence(__ATOMIC_RELEASE, "agent");  // publish (incl. own writes)
      __hip_atomic_store(epoch, target, __ATOMIC_RELAXED, __HIP_MEMORY_SCOPE_AGENT);
    }
    __syncthreads();
  } else {
    if (tid == 0) {
      __builtin_amdgcn_fence(__ATOMIC_RELEASE, "agent");  // publish this block's writes
      __hip_atomic_store(&flags[bx * 32], target, __ATOMIC_RELAXED,
                         __HIP_MEMORY_SCOPE_AGENT);
      while (__hip_atomic_load(epoch, __ATOMIC_RELAXED,
                               __HIP_MEMORY_SCOPE_AGENT) < target)
        __builtin_amdgcn_s_sleep(8);
      __builtin_amdgcn_fence(__ATOMIC_ACQUIRE, "agent");  // see everyone's writes
    }
    __syncthreads();
  }
}

__global__ __launch_bounds__(256) void k_fused(
    const float* __restrict__ x, const float* __restrict__ cent,
    const float* __restrict__ Ws1, const float* __restrict__ Wn1,
    const float* __restrict__ b1, const float* __restrict__ Ws2,
    const float* __restrict__ Wn2, const float* __restrict__ b2,
    const float* __restrict__ Wm1, const float* __restrict__ bm1,
    const float* __restrict__ Wm2, const float* __restrict__ bm2,
    float* __restrict__ n1, float* __restrict__ h1, float* __restrict__ h1T,
    float* __restrict__ n2, float* __restrict__ A, float* __restrict__ Bm,
    int* flags, int* epoch, float2* __restrict__ out) {
  __shared__ float smem[6144];  // 24 KB, reused across phases
  const int tid = threadIdx.x;
  const int bx = blockIdx.x;
  const int wv = tid >> 6;
  const int lane = tid & 63;

  // ---------------- Phase 1: edge features -> n1 ----------------
  if (bx < 32) {
    // per-feature exclusive scan of x[i,f]^2/||x_i||  (f = bx)
    float* invn_s = smem;        // 2048
    float* sc = smem + 2048;     // 256
    const int f = bx;
    for (int r = 0; r < 8; ++r) {
      int n = tid + 256 * r;
      const float4* xp = (const float4*)(x + n * 32);
      float s = 0.f;
#pragma unroll
      for (int q = 0; q < 8; ++q) {
        float4 v = xp[q];
        s += v.x * v.x + v.y * v.y + v.z * v.z + v.w * v.w;
      }
      invn_s[n] = rsqrtf(s);
    }
    __syncthreads();
    float sv[8], xv[8];
    float ts = 0.f;
#pragma unroll
    for (int r = 0; r < 8; ++r) {
      int i = tid * 8 + r;
      float xf = x[i * 32 + f];
      xv[r] = xf;
      float s = xf * xf * invn_s[i];
      sv[r] = s;
      ts += s;
    }
    sc[tid] = ts;
    __syncthreads();
    for (int off = 1; off < 256; off <<= 1) {
      float v = (tid >= off) ? sc[tid - off] : 0.f;
      __syncthreads();
      sc[tid] += v;
      __syncthreads();
    }
    float P = sc[tid] - ts;
#pragma unroll
    for (int r = 0; r < 8; ++r) {
      int i = tid * 8 + r;
      n1[i * N1S + f] = P * xv[r] * invn_s[i] * invdeg(i);
      P += sv[r];
    }
  } else {
    // centroid |diff| sums; wave handles pairs (p, 2047-p)
    float* cs = smem;  // 6144
    const float4* cp = (const float4*)cent;
    float4* csp = (float4*)cs;
#pragma unroll
    for (int q = 0; q < 6; ++q) csp[tid + 256 * q] = cp[tid + 256 * q];
    __syncthreads();
    const int wvg = (bx - 32) * 4 + wv;  // 0..895
#pragma unroll
    for (int rep = 0; rep < 2; ++rep) {
      const int p = wvg + rep * 896;
      if (p < 1024) {
#pragma unroll
        for (int pick = 0; pick < 2; ++pick) {
          const int j = pick ? (2047 - p) : p;
          const float cj0 = cs[j * 3 + 0], cj1 = cs[j * 3 + 1], cj2 = cs[j * 3 + 2];
          float s0 = 0.f, s1 = 0.f, s2 = 0.f;
          for (int i = lane; i < j; i += 64) {
            float c0 = cs[i * 3 + 0], c1 = cs[i * 3 + 1], c2 = cs[i * 3 + 2];
            s0 += c0 * fabsf(c0 - cj0);
            s1 += c1 * fabsf(c1 - cj1);
            s2 += c2 * fabsf(c2 - cj2);
          }
#pragma unroll
          for (int d = 32; d > 0; d >>= 1) {
            s0 += __shfl_down(s0, d);
            s1 += __shfl_down(s1, d);
            s2 += __shfl_down(s2, d);
          }
          if (lane == 0) {
            float idg = invdeg(j);
            n1[j * N1S + 32] = s0 * idg;
            n1[j * N1S + 33] = s1 * idg;
            n1[j * N1S + 34] = s2 * idg;
          }
        }
      }
    }
  }
  gbar(flags, epoch, 0);

  // ---------------- Phase 2: h1 (+ transposed copy h1T) ----------------
  {
    const int gw = bx * 4 + wv;  // 0..1023, wave-per-node, 2 rounds
    const int o = lane;
#pragma unroll
    for (int r = 0; r < 2; ++r) {
      const int n = __builtin_amdgcn_readfirstlane(gw + 1024 * r);
      float acc = b1[o];
      const float4* xr = (const float4*)(x + n * 32);
      const float4* nr = (const float4*)(n1 + n * N1S);
#pragma unroll
      for (int q = 0; q < 8; ++q) {
        float4 xv = xr[q];
        float4 nv = nr[q];
        acc += xv.x * Ws1[(4 * q + 0) * 64 + o] + nv.x * Wn1[(4 * q + 0) * 64 + o];
        acc += xv.y * Ws1[(4 * q + 1) * 64 + o] + nv.y * Wn1[(4 * q + 1) * 64 + o];
        acc += xv.z * Ws1[(4 * q + 2) * 64 + o] + nv.z * Wn1[(4 * q + 2) * 64 + o];
        acc += xv.w * Ws1[(4 * q + 3) * 64 + o] + nv.w * Wn1[(4 * q + 3) * 64 + o];
      }
      {
        float4 nv = nr[8];
        float c0 = cent[n * 3 + 0], c1 = cent[n * 3 + 1], c2 = cent[n * 3 + 2];
        acc += c0 * Ws1[32 * 64 + o] + nv.x * Wn1[32 * 64 + o];
        acc += c1 * Ws1[33 * 64 + o] + nv.y * Wn1[33 * 64 + o];
        acc += c2 * Ws1[34 * 64 + o] + nv.z * Wn1[34 * 64 + o];
      }
      h1[n * 64 + o] = acc;
      h1T[o * N_NODES + n] = acc;
    }
  }
  gbar(flags, epoch, 1);

  // ---------------- Phase 3: column scan of h1 -> n2 ----------------
  if (bx < 64) {
    float* sc = smem;
    const int o = bx;
    float sv[8];
    const float4* colp = (const float4*)(h1T + o * N_NODES);
    float4 a = colp[2 * tid];
    float4 b = colp[2 * tid + 1];
    sv[0] = a.x; sv[1] = a.y; sv[2] = a.z; sv[3] = a.w;
    sv[4] = b.x; sv[5] = b.y; sv[6] = b.z; sv[7] = b.w;
    float ts = 0.f;
#pragma unroll
    for (int r = 0; r < 8; ++r) ts += sv[r];
    sc[tid] = ts;
    __syncthreads();
    for (int off = 1; off < 256; off <<= 1) {
      float v = (tid >= off) ? sc[tid - off] : 0.f;
      __syncthreads();
      sc[tid] += v;
      __syncthreads();
    }
    float P = sc[tid] - ts;
#pragma unroll
    for (int r = 0; r < 8; ++r) {
      int i = tid * 8 + r;
      n2[i * 64 + o] = P * invdeg(i);
      P += sv[r];
    }
  }
  gbar(flags, epoch, 2);

  // ---------------- Phase 4: h2 -> A, Bm ----------------
  {
    const int gw = bx * 4 + wv;  // wave-per-node, 2 rounds
    const int o = lane & 31;
    const int half = lane >> 5;
#pragma unroll
    for (int r = 0; r < 2; ++r) {
      const int n = __builtin_amdgcn_readfirstlane(gw + 1024 * r);
      float acc = b2[o];
#pragma unroll
      for (int f = 0; f < 64; ++f)
        acc += h1[n * 64 + f] * Ws2[f * 32 + o] + n2[n * 64 + f] * Wn2[f * 32 + o];
      __syncthreads();
      smem[wv * 32 + o] = acc;  // both halves write identical value
      __syncthreads();
      float rr = half ? bm1[o] : 0.f;
#pragma unroll
      for (int f = 0; f < 32; ++f)
        rr += smem[wv * 32 + f] * Wm1[(half * 32 + f) * 32 + o];
      if (half)
        Bm[n * 32 + o] = rr;
      else
        A[n * 32 + o] = rr;
    }
  }
  gbar(flags, epoch, 3);

  // ---------------- Phase 5: per-edge head ----------------
  {
    float wd[32];
#pragma unroll
    for (int f = 0; f < 32; ++f) wd[f] = Wm2[f * 2 + 1] - Wm2[f * 2];
    const float db = bm2[1] - bm2[0];
    // 1152 chunks of 8 i-rows x 256 j-cols, linearized over jt: offset 16*jt*(jt+1)
    for (int c = bx; c < 1152; c += NB) {
      int jt = 0;
#pragma unroll
      for (int t = 1; t < 8; ++t)
        if (c >= 16 * t * (t + 1)) jt = t;
      const int ic = c - 16 * jt * (jt + 1);
      const int j0 = jt * 256;
      const int i0 = ic * 8;
      const int j = j0 + tid;
      float Br[32];
      const float4* bp = (const float4*)(Bm + j * 32);
#pragma unroll
      for (int q = 0; q < 8; ++q) {
        float4 v = bp[q];
        Br[4 * q + 0] = v.x;
        Br[4 * q + 1] = v.y;
        Br[4 * q + 2] = v.z;
        Br[4 * q + 3] = v.w;
      }
#pragma unroll
      for (int ii = 0; ii < 8; ++ii) {
        const int i = i0 + ii;
        const float* Ar = A + i * 32;  // uniform row -> scalar loads
        float d = db;
#pragma unroll
        for (int f = 0; f < 32; ++f)
          d += fmaxf(Ar[f] + Br[f], 0.f) * wd[f];
        if (i < j) {
          float p0 = 1.0f / (1.0f + __expf(d));
          int e = i * (2 * N_NODES - 1 - i) / 2 + (j - i - 1);
          out[e] = make_float2(p0, 1.0f - p0);
        }
      }
    }
  }
}

extern "C" void kernel_launch(void* const* d_in, const int* in_sizes, int n_in,
                              void* d_out, int out_size, void* d_ws, size_t ws_size,
                              hipStream_t stream) {
  const float* x    = (const float*)d_in[0];
  const float* cent = (const float*)d_in[1];
  const float* Ws1  = (const float*)d_in[2];
  const float* Wn1  = (const float*)d_in[3];
  const float* b1   = (const float*)d_in[4];
  const float* Ws2  = (const float*)d_in[5];
  const float* Wn2  = (const float*)d_in[6];
  const float* b2   = (const float*)d_in[7];
  const float* Wm1  = (const float*)d_in[8];
  const float* bm1  = (const float*)d_in[9];
  const float* Wm2  = (const float*)d_in[10];
  const float* bm2  = (const float*)d_in[11];

  int* flags = (int*)d_ws;                       // 256 flags, 128B apart (32 KB)
  int* epoch = flags + 256 * 32;                 // own line
  float* base = (float*)((char*)d_ws + 65536);   // data region after 64 KB
  float* n1  = base;                    // 2048*36
  float* h1  = n1 + 2048 * N1S;         // 2048*64
  float* h1T = h1 + 2048 * 64;          // 64*2048
  float* n2  = h1T + 2048 * 64;         // 2048*64
  float* A   = n2 + 2048 * 64;          // 2048*32
  float* Bm  = A + 2048 * 32;           // 2048*32

  hipMemsetAsync(d_ws, 0, 36864, stream);  // zero flags + epoch (capturable)
  k_fused<<<NB, 256, 0, stream>>>(x, cent, Ws1, Wn1, b1, Ws2, Wn2, b2,
                                  Wm1, bm1, Wm2, bm2,
                                  n1, h1, h1T, n2, A, Bm, flags, epoch,
                                  (float2*)d_out);
}